// Round 1
// baseline (230.662 us; speedup 1.0000x reference)
//
#include <hip/hip_runtime.h>
#include <math.h>

#define SS 64
#define BB 32
#define DD 586
#define DE 583    // emb columns
#define U1 114    // length after conv1+pool1
#define U2 38     // after pool2
#define T3 36     // conv3 out length
#define NTOK 18752  // B*D elements per s

// ---------------- Kernel 1: gather + BN-stats collapse ----------------
// The 4 BatchNorm layers are affine in x0 per channel s; normalization cancels
// offsets, so x_final = alpha[s]*x0 + (beta[3][s] - alpha[s]*m0[s]).
__global__ __launch_bounds__(256) void k_stats(
    const int* __restrict__ tokens, const float* __restrict__ emb,
    const float* __restrict__ pos, const float* __restrict__ gamma,
    const float* __restrict__ beta, float* __restrict__ alpha,
    float* __restrict__ delta)
{
  const int s = blockIdx.x;
  const int tid = threadIdx.x;
  const float sqrtD = 24.207436873820409f;  // sqrt(586)
  __shared__ int stok[BB];
  if (tid < BB) stok[tid] = tokens[s*BB + tid];
  __syncthreads();
  double sum = 0.0, sq = 0.0;
  for (int idx = tid; idx < BB*DE; idx += 256) {
    int b = idx / DE;
    int d = idx - b*DE;
    float v = emb[(size_t)stok[b]*DE + d] * sqrtD;
    sum += v; sq += (double)v * v;
  }
  if (tid < BB*3) {  // tiled pos: pos[(s*B+b)*3+j], tid = b*3+j
    float v = pos[s*BB*3 + tid];
    sum += v; sq += (double)v * v;
  }
  for (int off = 32; off > 0; off >>= 1) {
    sum += __shfl_down(sum, off);
    sq  += __shfl_down(sq, off);
  }
  __shared__ double rs_[4], rq_[4];
  int wid = tid >> 6;
  if ((tid & 63) == 0) { rs_[wid] = sum; rq_[wid] = sq; }
  __syncthreads();
  if (tid == 0) {
    double St = rs_[0]+rs_[1]+rs_[2]+rs_[3];
    double Qt = rq_[0]+rq_[1]+rq_[2]+rq_[3];
    double m0d = St / (double)NTOK;
    float m0 = (float)m0d;
    float v0 = (float)(Qt / (double)NTOK - m0d*m0d);
    float a = 1.0f;
    for (int l = 0; l < 4; ++l) {
      float rs = 1.0f / sqrtf(a*a*v0 + 1e-5f);
      a = gamma[l*SS + s] * rs * a;
    }
    alpha[s] = a;
    delta[s] = beta[3*SS + s] - a * m0;
  }
}

// ---------------- Kernel 2: fused conv1 + avgpool(5) ----------------
// out2[o,u] = b1[o] + sum_{c,m} x[c,5u+m] * wp[o,c,m],
// wp[o,c,m] = (1/5) * sum_{k=max(0,m-4)}^{min(16,m)} w1[o,c,k]  (21 taps).
// Grid: (s, c-group of 8). Partial sums over c go to ws; bias added in k3.
__global__ __launch_bounds__(256) void k_conv1(
    const int* __restrict__ tokens, const float* __restrict__ emb,
    const float* __restrict__ pos, const float* __restrict__ w1,
    const float* __restrict__ alpha, const float* __restrict__ delta,
    float* __restrict__ part)
{
  const int s = blockIdx.x;
  const int g = blockIdx.y;      // 4 groups x 8 input channels
  const int tid = threadIdx.x;
  const float sqrtD = 24.207436873820409f;
  __shared__ float xs[8*587];                     // 8 rows, +1 pad stride
  __shared__ __align__(16) float wp[8*21*16];     // [cc][m][o], o contiguous
  __shared__ int stok[8];
  if (tid < 8) stok[tid] = tokens[s*BB + g*8 + tid];
  __syncthreads();
  const float al = alpha[s], de = delta[s];
  for (int idx = tid; idx < 8*DD; idx += 256) {
    int cc = idx / DD;
    int d = idx - cc*DD;
    float v;
    if (d < DE) v = emb[(size_t)stok[cc]*DE + d] * sqrtD;
    else        v = pos[(s*BB + g*8 + cc)*3 + (d - DE)];
    xs[cc*587 + d] = al * v + de;
  }
  for (int idx = tid; idx < 8*21*16; idx += 256) {
    int o  = idx & 15;
    int r  = idx >> 4;        // cc*21 + m
    int cc = r / 21;
    int m  = r - cc*21;
    int c  = g*8 + cc;
    int k0 = m - 4; if (k0 < 0) k0 = 0;
    int k1 = m;     if (k1 > 16) k1 = 16;
    float acc = 0.f;
    for (int k = k0; k <= k1; ++k) acc += w1[(o*BB + c)*17 + k];
    wp[idx] = acc * 0.2f;
  }
  __syncthreads();
  const int lane = tid & 63;
  const int og1  = tid >> 6;           // 4 output channels per thread
  const int u0   = lane;               // always < 114
  const bool u1v = (lane + 64) < U1;
  const int u1   = u1v ? (lane + 64) : (U1 - 1);
  float a00=0,a01=0,a02=0,a03=0, a10=0,a11=0,a12=0,a13=0;
  for (int cc = 0; cc < 8; ++cc) {
    const float* xr = &xs[cc*587];
    const float4* wr = (const float4*)&wp[cc*21*16 + og1*4];
    #pragma unroll
    for (int m = 0; m < 21; ++m) {
      float4 w4 = wr[m*4];             // wave-uniform -> LDS broadcast
      float x0 = xr[5*u0 + m];         // stride-5 -> conflict-free
      float x1 = xr[5*u1 + m];
      a00 += x0*w4.x; a01 += x0*w4.y; a02 += x0*w4.z; a03 += x0*w4.w;
      a10 += x1*w4.x; a11 += x1*w4.y; a12 += x1*w4.z; a13 += x1*w4.w;
    }
  }
  float* pb = part + (size_t)(g*SS + s)*16*U1;
  float r0[4] = {a00,a01,a02,a03};
  float r1[4] = {a10,a11,a12,a13};
  #pragma unroll
  for (int oo = 0; oo < 4; ++oo) {
    int o = og1*4 + oo;
    pb[o*U1 + u0] = r0[oo];
    if (u1v) pb[o*U1 + u1] = r1[oo];
  }
}

// ---------------- Kernel 3: pool2 + conv2 + conv3 + dense + argmax ----------------
__global__ __launch_bounds__(256) void k_tail(
    const float* __restrict__ part, const float* __restrict__ b1,
    const float* __restrict__ w2, const float* __restrict__ b2,
    const float* __restrict__ w3, const float* __restrict__ b3,
    const float* __restrict__ wl, const float* __restrict__ bl,
    float* __restrict__ out)
{
  const int s = blockIdx.x;
  const int tid = threadIdx.x;
  __shared__ float o2[16*U1];
  __shared__ float p2[16*U2];
  __shared__ float o4[8*U2];
  __shared__ float o5[32*T3];
  __shared__ float wlb[128*37];   // +1 pad: stride-37 kills bank conflicts
  __shared__ float blb[128];
  for (int idx = tid; idx < 16*U1; idx += 256) {
    int o = idx / U1;
    float acc = b1[o];
    #pragma unroll
    for (int gg = 0; gg < 4; ++gg)
      acc += part[(size_t)(gg*SS + s)*16*U1 + idx];
    o2[idx] = acc;
  }
  for (int idx = tid; idx < 128*36; idx += 256) {
    int v = idx / 36; int t = idx - v*36;
    wlb[v*37 + t] = wl[idx];
  }
  if (tid < 128) blb[tid] = bl[tid];
  __syncthreads();
  // avgpool(3) first: conv2 has kernel 1, so it commutes with the pool.
  for (int idx = tid; idx < 16*U2; idx += 256) {
    int o = idx / U2; int v = idx - o*U2;
    p2[idx] = (o2[o*U1 + 3*v] + o2[o*U1 + 3*v+1] + o2[o*U1 + 3*v+2]) * (1.f/3.f);
  }
  __syncthreads();
  for (int idx = tid; idx < 8*U2; idx += 256) {
    int p = idx / U2; int v = idx - p*U2;
    float acc = b2[p];
    #pragma unroll
    for (int o = 0; o < 16; ++o) acc += p2[o*U2 + v] * w2[p*16 + o];
    o4[idx] = acc;
  }
  __syncthreads();
  for (int idx = tid; idx < 32*T3; idx += 256) {
    int q = idx / T3; int t = idx - q*T3;
    float acc = b3[q];
    #pragma unroll
    for (int p = 0; p < 8; ++p) {
      acc += o4[p*U2 + t    ] * w3[(q*8+p)*3 + 0]
           + o4[p*U2 + t + 1] * w3[(q*8+p)*3 + 1]
           + o4[p*U2 + t + 2] * w3[(q*8+p)*3 + 2];
    }
    o5[idx] = acc;
  }
  __syncthreads();
  // logits + argmax. thread: q = tid>>3, vs = tid&7; v = vs + 8*i (ascending
  // per thread; (max,min-idx) merge preserves first-max tie-break).
  const int q = tid >> 3, vs = tid & 7;
  float best = -1e30f; int bidx = 0;
  for (int i = 0; i < 16; ++i) {
    int v = vs + 8*i;
    float acc = blb[v];
    const float* wr = &wlb[v*37];
    const float* orow = &o5[q*T3];
    #pragma unroll
    for (int t = 0; t < 36; ++t) acc += orow[t] * wr[t];
    if (acc > best) { best = acc; bidx = v; }
  }
  #pragma unroll
  for (int off = 1; off < 8; off <<= 1) {
    float ov = __shfl_xor(best, off);
    int oi = __shfl_xor(bidx, off);
    if (ov > best || (ov == best && oi < bidx)) { best = ov; bidx = oi; }
  }
  if (vs == 0) out[s*BB + q] = (float)bidx;
}

extern "C" void kernel_launch(void* const* d_in, const int* in_sizes, int n_in,
                              void* d_out, int out_size, void* d_ws, size_t ws_size,
                              hipStream_t stream)
{
  const int*   tokens = (const int*)  d_in[0];
  const float* emb    = (const float*)d_in[1];
  const float* pos    = (const float*)d_in[2];
  const float* gamma  = (const float*)d_in[3];
  const float* beta   = (const float*)d_in[4];
  const float* w1     = (const float*)d_in[5];
  const float* b1     = (const float*)d_in[6];
  const float* w2     = (const float*)d_in[7];
  const float* b2     = (const float*)d_in[8];
  const float* w3     = (const float*)d_in[9];
  const float* b3     = (const float*)d_in[10];
  const float* wl     = (const float*)d_in[11];
  const float* bl     = (const float*)d_in[12];
  float* out = (float*)d_out;

  float* wsf   = (float*)d_ws;
  float* alpha = wsf;            // 64
  float* delta = wsf + 64;       // 64
  float* part  = wsf + 128;      // 4*64*16*114 floats = 1.87 MB

  k_stats<<<dim3(SS), dim3(256), 0, stream>>>(tokens, emb, pos, gamma, beta,
                                              alpha, delta);
  k_conv1<<<dim3(SS, 4), dim3(256), 0, stream>>>(tokens, emb, pos, w1,
                                                 alpha, delta, part);
  k_tail<<<dim3(SS), dim3(256), 0, stream>>>(part, b1, w2, b2, w3, b3,
                                             wl, bl, out);
}

// Round 3
// 230.469 us; speedup vs baseline: 1.0008x; 1.0008x over previous
//
#include <hip/hip_runtime.h>
#include <math.h>

#define SS 64
#define BB 32
#define DD 586
#define DE 583    // emb columns
#define U1 114    // length after conv1+pool1
#define U2 38     // after pool2
#define T3 36     // conv3 out length
#define NTOK 18752  // B*D elements per s
#define NT 512      // threads per block

// One block per s. Phases:
//  A: gather all 32 rows (stats only, no staging), collapse 4 BN layers to
//     per-s affine (alpha, delta). wlb/blb staged concurrently.
//  B: 4 groups of 8 input channels: re-gather 8 rows -> LDS (affine applied),
//     fused conv1(k=17)+avgpool(5) as stride-5 conv with pre-summed 21-tap
//     kernel; accumulate in registers across groups; write o2 (+b1).
//  C: avgpool(3) (commutes with k=1 conv2), conv2, conv3, dense, argmax.
//     NOTE: phase-C ranges exceed NT (608, 1152) -> MUST be grid-stride loops.
__global__ __launch_bounds__(NT) void k_fused(
    const int* __restrict__ tokens, const float* __restrict__ emb,
    const float* __restrict__ pos, const float* __restrict__ gamma,
    const float* __restrict__ beta, const float* __restrict__ w1,
    const float* __restrict__ b1, const float* __restrict__ w2,
    const float* __restrict__ b2, const float* __restrict__ w3,
    const float* __restrict__ b3, const float* __restrict__ wl,
    const float* __restrict__ bl, float* __restrict__ out)
{
  const int s = blockIdx.x;
  const int tid = threadIdx.x;
  const float sqrtD = 24.207436873820409f;  // sqrt(586)

  __shared__ union {
    float xs[8*587];          // phase B staging, +1 pad stride (18784 B)
    struct {                  // phase C overlays (2064 floats)
      float p2[16*U2];
      float o4[8*U2];
      float o5[32*T3];
    } t;
  } u;
  __shared__ __align__(16) float wp[8*21*16];  // [cc][m][o], o contiguous
  __shared__ float o2[16*U1];
  __shared__ float wlb[128*37];  // +1 pad: stride-37 -> conflict-free
  __shared__ float blb[128];
  __shared__ int stok[BB];
  __shared__ double rs_[8], rq_[8];
  __shared__ float sAl, sDe;

  if (tid < BB) stok[tid] = tokens[s*BB + tid];
  // stage dense weights early (overlaps with the phase-A gather)
  for (int idx = tid; idx < 128*36; idx += NT) {
    int v = idx / 36; int t = idx - v*36;
    wlb[v*37 + t] = wl[idx];
  }
  if (tid < 128) blb[tid] = bl[tid];
  __syncthreads();

  // ---- Phase A: stats over all 32 rows (4-way unrolled for MLP) ----
  double s0=0.0,s1=0.0,s2=0.0,s3=0.0, q0=0.0,q1=0.0,q2=0.0,q3=0.0;
  int idx = tid;
  for (; idx + 3*NT < BB*DE; idx += 4*NT) {
    int i0=idx, i1=idx+NT, i2=idx+2*NT, i3=idx+3*NT;
    int b0=i0/DE, b1_=i1/DE, b2_=i2/DE, b3_=i3/DE;
    float v0 = emb[(size_t)stok[b0]*DE + (i0-b0*DE)] * sqrtD;
    float v1 = emb[(size_t)stok[b1_]*DE + (i1-b1_*DE)] * sqrtD;
    float v2 = emb[(size_t)stok[b2_]*DE + (i2-b2_*DE)] * sqrtD;
    float v3 = emb[(size_t)stok[b3_]*DE + (i3-b3_*DE)] * sqrtD;
    s0+=v0; q0+=(double)v0*v0; s1+=v1; q1+=(double)v1*v1;
    s2+=v2; q2+=(double)v2*v2; s3+=v3; q3+=(double)v3*v3;
  }
  for (; idx < BB*DE; idx += NT) {
    int b = idx/DE;
    float v = emb[(size_t)stok[b]*DE + (idx-b*DE)] * sqrtD;
    s0+=v; q0+=(double)v*v;
  }
  if (tid < BB*3) {  // pos tiled over b: pos[(s*B+b)*3+j]
    float v = pos[s*BB*3 + tid];
    s0+=v; q0+=(double)v*v;
  }
  double sum = (s0+s1)+(s2+s3);
  double sq  = (q0+q1)+(q2+q3);
  for (int off = 32; off > 0; off >>= 1) {
    sum += __shfl_down(sum, off);
    sq  += __shfl_down(sq, off);
  }
  int wid = tid >> 6;
  if ((tid & 63) == 0) { rs_[wid] = sum; rq_[wid] = sq; }
  __syncthreads();
  if (tid == 0) {
    double St=0.0, Qt=0.0;
    for (int w = 0; w < 8; ++w) { St += rs_[w]; Qt += rq_[w]; }
    double m0d = St / (double)NTOK;
    float m0 = (float)m0d;
    float v0 = (float)(Qt / (double)NTOK - m0d*m0d);
    float a = 1.0f;
    for (int l = 0; l < 4; ++l) {
      float r = 1.0f / sqrtf(a*a*v0 + 1e-5f);
      a = gamma[l*SS + s] * r * a;
    }
    sAl = a;
    sDe = beta[3*SS + s] - a * m0;
  }
  __syncthreads();
  const float al = sAl, de = sDe;

  // ---- Phase B: fused conv1 + avgpool(5), 4 groups of 8 channels ----
  const int lane = tid & 63;
  const int og   = tid >> 6;            // 8 waves -> 2 output channels each
  const int u0   = lane;                // < 114 always
  const bool u1v = (lane + 64) < U1;
  const int u1   = u1v ? (lane + 64) : (U1 - 1);
  float a00=0.f, a01=0.f, a10=0.f, a11=0.f;  // [u0,u1] x [o=2og, 2og+1]
  for (int g = 0; g < 4; ++g) {
    __syncthreads();   // WAR: previous group's readers done before restage
    for (int i = tid; i < 8*DD; i += NT) {
      int cc = i / DD;
      int d = i - cc*DD;
      float v;
      if (d < DE) v = emb[(size_t)stok[g*8+cc]*DE + d] * sqrtD;
      else        v = pos[(s*BB + g*8 + cc)*3 + (d - DE)];
      u.xs[cc*587 + d] = al * v + de;
    }
    for (int i = tid; i < 8*21*16; i += NT) {
      int o  = i & 15;
      int r  = i >> 4;        // cc*21 + m
      int cc = r / 21;
      int m  = r - cc*21;
      int c  = g*8 + cc;
      int k0 = m - 4;  if (k0 < 0) k0 = 0;
      int k1 = m;      if (k1 > 16) k1 = 16;
      float acc = 0.f;
      for (int k = k0; k <= k1; ++k) acc += w1[(o*BB + c)*17 + k];
      wp[i] = acc * 0.2f;
    }
    __syncthreads();
    for (int cc = 0; cc < 8; ++cc) {
      const float* xr = &u.xs[cc*587];
      const float2* wr = (const float2*)&wp[cc*21*16 + og*2];
      #pragma unroll
      for (int m = 0; m < 21; ++m) {
        float2 w2v = wr[m*8];           // wave-uniform -> LDS broadcast
        float x0 = xr[5*u0 + m];        // stride 5 coprime 32 -> conflict-free
        float x1 = xr[5*u1 + m];
        a00 += x0*w2v.x; a01 += x0*w2v.y;
        a10 += x1*w2v.x; a11 += x1*w2v.y;
      }
    }
  }
  {
    int o0 = og*2, o1 = og*2 + 1;
    o2[o0*U1 + u0] = a00 + b1[o0];
    o2[o1*U1 + u0] = a01 + b1[o1];
    if (u1v) {
      o2[o0*U1 + u1] = a10 + b1[o0];
      o2[o1*U1 + u1] = a11 + b1[o1];
    }
  }
  __syncthreads();

  // ---- Phase C: pool2 -> conv2 -> conv3 -> dense -> argmax ----
  for (int i2 = tid; i2 < 16*U2; i2 += NT) {   // 608 > NT: loop required
    int o = i2 / U2; int v = i2 - o*U2;
    u.t.p2[i2] = (o2[o*U1 + 3*v] + o2[o*U1 + 3*v+1] + o2[o*U1 + 3*v+2]) * (1.f/3.f);
  }
  __syncthreads();
  for (int i2 = tid; i2 < 8*U2; i2 += NT) {
    int p = i2 / U2; int v = i2 - p*U2;
    float acc = b2[p];
    #pragma unroll
    for (int o = 0; o < 16; ++o) acc += u.t.p2[o*U2 + v] * w2[p*16 + o];
    u.t.o4[i2] = acc;
  }
  __syncthreads();
  for (int i2 = tid; i2 < 32*T3; i2 += NT) {   // 1152 > NT: loop required
    int q = i2 / T3; int t = i2 - q*T3;
    float acc = b3[q];
    #pragma unroll
    for (int p = 0; p < 8; ++p) {
      acc += u.t.o4[p*U2 + t    ] * w3[(q*8+p)*3 + 0]
           + u.t.o4[p*U2 + t + 1] * w3[(q*8+p)*3 + 1]
           + u.t.o4[p*U2 + t + 2] * w3[(q*8+p)*3 + 2];
    }
    u.t.o5[i2] = acc;
  }
  __syncthreads();
  // q = tid>>4 (32 rows), vs = tid&15; v = vs + 16*i ascending per thread;
  // (max, min-idx) merge preserves jnp.argmax first-max tie-break.
  const int q = tid >> 4, vs = tid & 15;
  float best = -1e30f; int bidx = 0;
  const float* orow = &u.t.o5[q*T3];
  for (int i = 0; i < 8; ++i) {
    int v = vs + 16*i;
    float acc = blb[v];
    const float* wr = &wlb[v*37];
    #pragma unroll
    for (int t = 0; t < 36; ++t) acc += orow[t] * wr[t];
    if (acc > best) { best = acc; bidx = v; }
  }
  #pragma unroll
  for (int off = 1; off < 16; off <<= 1) {
    float ov = __shfl_xor(best, off);
    int oi = __shfl_xor(bidx, off);
    if (ov > best || (ov == best && oi < bidx)) { best = ov; bidx = oi; }
  }
  if (vs == 0) out[s*BB + q] = (float)bidx;
}

extern "C" void kernel_launch(void* const* d_in, const int* in_sizes, int n_in,
                              void* d_out, int out_size, void* d_ws, size_t ws_size,
                              hipStream_t stream)
{
  const int*   tokens = (const int*)  d_in[0];
  const float* emb    = (const float*)d_in[1];
  const float* pos    = (const float*)d_in[2];
  const float* gamma  = (const float*)d_in[3];
  const float* beta   = (const float*)d_in[4];
  const float* w1     = (const float*)d_in[5];
  const float* b1     = (const float*)d_in[6];
  const float* w2     = (const float*)d_in[7];
  const float* b2     = (const float*)d_in[8];
  const float* w3     = (const float*)d_in[9];
  const float* b3     = (const float*)d_in[10];
  const float* wl     = (const float*)d_in[11];
  const float* bl     = (const float*)d_in[12];
  float* out = (float*)d_out;

  k_fused<<<dim3(SS), dim3(NT), 0, stream>>>(tokens, emb, pos, gamma, beta,
                                             w1, b1, w2, b2, w3, b3, wl, bl,
                                             out);
}

// Round 5
// 201.617 us; speedup vs baseline: 1.1441x; 1.1431x over previous
//
#include <hip/hip_runtime.h>
#include <math.h>

#define SS 64
#define BB 32
#define DD 586
#define DE 583      // emb columns
#define U1 114      // length after conv1+pool1
#define U2 38       // after pool2
#define T3 36       // conv3 out length
#define NTOK 18752  // B*D elements per s
#define NSTAT (SS*BB)      // 2048 row-stat blocks
#define WPN (32*21*16)     // 10752 pre-pooled conv1 weights [c][m][o]
#define WPBLK (WPN/256)    // 42
#define SQD 24.207436873820409f  // sqrt(586)

// ws layout:
//   double rowsumd[2048]; double rowsqd[2048];
//   float  wp[32*21*16];       // [c][m][o], o contiguous
//   float  part[4][64][16][114];

// ---- K1: per-row stats + conv1 weight pre-sums (independent, big grid) ----
__global__ __launch_bounds__(256) void k_pre(
    const int* __restrict__ tokens, const float* __restrict__ emb,
    const float* __restrict__ pos, const float* __restrict__ w1,
    double* __restrict__ rowsumd, double* __restrict__ rowsqd,
    float* __restrict__ wp)
{
  const int bid = blockIdx.x, tid = threadIdx.x;
  if (bid < NSTAT) {
    const int s = bid >> 5, b = bid & 31;
    const int tok = tokens[s*BB + b];
    const float* row = emb + (size_t)tok*DE;
    double sum = 0.0, sq = 0.0;
    for (int d = tid; d < DE; d += 256) {
      float v = row[d] * SQD;
      sum += v; sq += (double)v*v;
    }
    if (tid < 3) {
      float v = pos[(s*BB + b)*3 + tid];
      sum += v; sq += (double)v*v;
    }
    for (int off = 32; off > 0; off >>= 1) {
      sum += __shfl_down(sum, off);
      sq  += __shfl_down(sq, off);
    }
    __shared__ double rs[4], rq[4];
    if ((tid & 63) == 0) { rs[tid>>6] = sum; rq[tid>>6] = sq; }
    __syncthreads();
    if (tid == 0) {
      rowsumd[bid] = (rs[0]+rs[1]) + (rs[2]+rs[3]);
      rowsqd[bid]  = (rq[0]+rq[1]) + (rq[2]+rq[3]);
    }
  } else {
    // wp[c][m][o] = (1/5) * sum_{k=max(0,m-4)}^{min(16,m)} w1[o][c][k]
    const int idx = (bid - NSTAT)*256 + tid;   // 0..10751
    const int o = idx & 15;
    const int r = idx >> 4;        // c*21 + m
    const int m = r % 21;
    const int c = r / 21;
    int k0 = m - 4;  if (k0 < 0)  k0 = 0;
    int k1 = m;      if (k1 > 16) k1 = 16;
    float acc = 0.f;
    for (int k = k0; k <= k1; ++k) acc += w1[(o*BB + c)*17 + k];
    wp[idx] = acc * 0.2f;
  }
}

// ---- K2: fused conv1+avgpool(5) on AFFINE x (R1-proven math order) ----
// grid (s=64, g=4); 256 threads: up=tid&127 -> u, oh=tid>>7 -> o in [8oh,8oh+8)
__global__ __launch_bounds__(256) void k_conv(
    const int* __restrict__ tokens, const float* __restrict__ emb,
    const float* __restrict__ pos, const float* __restrict__ wp,
    const double* __restrict__ rowsumd, const double* __restrict__ rowsqd,
    const float* __restrict__ gamma, const float* __restrict__ beta,
    float* __restrict__ part)
{
  const int s = blockIdx.x, g = blockIdx.y;
  const int tid = threadIdx.x;
  __shared__ float xs[8*DD];
  __shared__ int stok[8];
  __shared__ float sAl, sDe;
  if (tid < 8) stok[tid] = tokens[s*BB + g*8 + tid];
  __syncthreads();
  for (int i = tid; i < 8*DD; i += 256) {
    int cc = i / DD, d = i - cc*DD;
    float v = (d < DE) ? emb[(size_t)stok[cc]*DE + d] * SQD
                       : pos[(s*BB + g*8 + cc)*3 + (d - DE)];
    xs[i] = v;   // raw (affine applied at register load; element-wise same)
  }
  // lanes 0..31 reduce the 32 per-row double sums -> al, de (redundant per
  // block but double-accumulated => identical across blocks)
  if (tid < 32) {
    double sm = rowsumd[s*BB + tid], qq = rowsqd[s*BB + tid];
    for (int off = 16; off > 0; off >>= 1) {
      sm += __shfl_down(sm, off, 32);
      qq += __shfl_down(qq, off, 32);
    }
    if (tid == 0) {
      double m0d = sm / (double)NTOK;
      float m0 = (float)m0d;
      float v0 = (float)(qq / (double)NTOK - m0d*m0d);
      float a = 1.0f;
      for (int l = 0; l < 4; ++l) {
        float r = 1.0f / sqrtf(a*a*v0 + 1e-5f);
        a = gamma[l*SS + s] * r * a;
      }
      sAl = a;
      sDe = beta[3*SS + s] - a*m0;
    }
  }
  __syncthreads();
  const float al = sAl, de = sDe;
  const int up = tid & 127;
  const int oh = __builtin_amdgcn_readfirstlane(tid >> 7);  // wave-uniform
  const int u  = (up < U1) ? up : (U1 - 1);
  float acc[8] = {0,0,0,0,0,0,0,0};
  for (int cc = 0; cc < 8; ++cc) {
    const float* xr = &xs[cc*DD + 5*u];   // stride-5 lanes: conflict-free
    float xv[21];
    #pragma unroll
    for (int m = 0; m < 21; ++m) { float v = xr[m]; xv[m] = al * v + de; }
    // uniform (SGPR) base -> scalar loads, no LDS traffic for weights
    const float* wr = wp + ((g*8 + cc)*21)*16 + oh*8;
    #pragma unroll
    for (int m = 0; m < 21; ++m) {
      #pragma unroll
      for (int j = 0; j < 8; ++j) acc[j] += xv[m] * wr[m*16 + j];
    }
  }
  if (up < U1) {
    float* pb = part + ((size_t)(g*SS + s)*16 + oh*8)*U1 + up;
    #pragma unroll
    for (int j = 0; j < 8; ++j) pb[j*U1] = acc[j];  // coalesced over up
  }
}

// ---- K3: assembly (+b1), pool2, conv2, conv3, dense, argmax ----
__global__ __launch_bounds__(256) void k_tail(
    const float* __restrict__ part, const float* __restrict__ b1,
    const float* __restrict__ w2, const float* __restrict__ b2,
    const float* __restrict__ w3, const float* __restrict__ b3,
    const float* __restrict__ wl, const float* __restrict__ bl,
    float* __restrict__ out)
{
  const int s = blockIdx.x, tid = threadIdx.x;
  __shared__ float o2[16*U1];
  __shared__ float p2[16*U2];
  __shared__ float o4[8*U2];
  __shared__ float o5[32*T3];
  __shared__ float wlb[128*37];   // +1 pad: conflict-free
  __shared__ float blb[128];
  for (int idx = tid; idx < 128*36; idx += 256) {
    int v = idx / 36, t = idx - v*36;
    wlb[v*37 + t] = wl[idx];
  }
  if (tid < 128) blb[tid] = bl[tid];
  for (int idx = tid; idx < 16*U1; idx += 256) {
    int o = idx / U1;
    float acc = b1[o];
    acc += part[(size_t)(0*SS + s)*16*U1 + idx];
    acc += part[(size_t)(1*SS + s)*16*U1 + idx];
    acc += part[(size_t)(2*SS + s)*16*U1 + idx];
    acc += part[(size_t)(3*SS + s)*16*U1 + idx];
    o2[idx] = acc;
  }
  __syncthreads();
  for (int i2 = tid; i2 < 16*U2; i2 += 256) {   // 608 > 256: loop required
    int o = i2 / U2, v = i2 - o*U2;
    p2[i2] = (o2[o*U1 + 3*v] + o2[o*U1 + 3*v+1] + o2[o*U1 + 3*v+2]) * (1.f/3.f);
  }
  __syncthreads();
  for (int i2 = tid; i2 < 8*U2; i2 += 256) {    // 304 > 256: loop required
    int p = i2 / U2, v = i2 - p*U2;
    float acc = b2[p];
    #pragma unroll
    for (int o = 0; o < 16; ++o) acc += p2[o*U2 + v] * w2[p*16 + o];
    o4[i2] = acc;
  }
  __syncthreads();
  for (int i2 = tid; i2 < 32*T3; i2 += 256) {   // 1152 > 256: loop required
    int q = i2 / T3, t = i2 - q*T3;
    float acc = b3[q];
    #pragma unroll
    for (int p = 0; p < 8; ++p) {
      acc += o4[p*U2 + t    ] * w3[(q*8+p)*3 + 0]
           + o4[p*U2 + t + 1] * w3[(q*8+p)*3 + 1]
           + o4[p*U2 + t + 2] * w3[(q*8+p)*3 + 2];
    }
    o5[i2] = acc;
  }
  __syncthreads();
  // 256 threads: q = tid>>3 covers 0..31, vs = tid&7; v = vs + 8*i ascending
  // per thread; (max,min-idx) merge preserves first-max tie-break.
  const int q = tid >> 3, vs = tid & 7;
  float best = -1e30f; int bidx = 0;
  const float* orow = &o5[q*T3];
  for (int i = 0; i < 16; ++i) {
    int v = vs + 8*i;
    float acc = blb[v];
    const float* wr = &wlb[v*37];
    #pragma unroll
    for (int t = 0; t < 36; ++t) acc += orow[t] * wr[t];
    if (acc > best) { best = acc; bidx = v; }
  }
  #pragma unroll
  for (int off = 1; off < 8; off <<= 1) {
    float ov = __shfl_xor(best, off);
    int oi = __shfl_xor(bidx, off);
    if (ov > best || (ov == best && oi < bidx)) { best = ov; bidx = oi; }
  }
  if (vs == 0) out[s*BB + q] = (float)bidx;
}

extern "C" void kernel_launch(void* const* d_in, const int* in_sizes, int n_in,
                              void* d_out, int out_size, void* d_ws, size_t ws_size,
                              hipStream_t stream)
{
  const int*   tokens = (const int*)  d_in[0];
  const float* emb    = (const float*)d_in[1];
  const float* pos    = (const float*)d_in[2];
  const float* gamma  = (const float*)d_in[3];
  const float* beta   = (const float*)d_in[4];
  const float* w1     = (const float*)d_in[5];
  const float* b1     = (const float*)d_in[6];
  const float* w2     = (const float*)d_in[7];
  const float* b2     = (const float*)d_in[8];
  const float* w3     = (const float*)d_in[9];
  const float* b3     = (const float*)d_in[10];
  const float* wl     = (const float*)d_in[11];
  const float* bl     = (const float*)d_in[12];
  float* out = (float*)d_out;

  double* rowsumd = (double*)d_ws;            // 2048
  double* rowsqd  = rowsumd + NSTAT;          // 2048
  float*  wp      = (float*)(rowsqd + NSTAT); // 10752
  float*  part    = wp + WPN;                 // 4*64*16*114

  k_pre<<<dim3(NSTAT + WPBLK), dim3(256), 0, stream>>>(
      tokens, emb, pos, w1, rowsumd, rowsqd, wp);
  k_conv<<<dim3(SS, 4), dim3(256), 0, stream>>>(
      tokens, emb, pos, wp, rowsumd, rowsqd, gamma, beta, part);
  k_tail<<<dim3(SS), dim3(256), 0, stream>>>(part, b1, w2, b2, w3, b3,
                                             wl, bl, out);
}

// Round 6
// 193.503 us; speedup vs baseline: 1.1920x; 1.0419x over previous
//
#include <hip/hip_runtime.h>
#include <math.h>

#define SS 64
#define BB 32
#define DD 586
#define DE 583      // emb columns
#define U1 114      // length after conv1+pool1
#define U2 38       // after pool2
#define T3 36       // conv3 out length
#define NTOK 18752  // B*D elements per s
#define NSTAT (SS*BB)
#define SQD 24.207436873820409f  // sqrt(586)

// ws layout:
//   double rowsumd[2048]; double rowsqd[2048];
//   float  part[4][64][16][114];   // raw conv1+pool1 partials (no affine)

// ---- K1: gather once -> row stats + raw fused conv1+avgpool(5) ----
// grid (s=64, g=4); 256 threads.
// Deferred affine: conv(al*x+de) = al*conv(x) + de*wsum, so conv runs on RAW
// x and stats are computed from the SAME staged tile (single gather).
// Conv identity: out_raw[o,u] = 0.2 * sum_{c,k} w1[o,c,k] * xw[c,k],
//   xw[c,k] = sum_{m=k..k+4} x[c,5u+m]   (k=0..16)
__global__ __launch_bounds__(256) void k_main(
    const int* __restrict__ tokens, const float* __restrict__ emb,
    const float* __restrict__ pos, const float* __restrict__ w1,
    double* __restrict__ rowsumd, double* __restrict__ rowsqd,
    float* __restrict__ part)
{
  const int s = blockIdx.x, g = blockIdx.y;
  const int tid = threadIdx.x;
  __shared__ float xs[8*DD];
  __shared__ int stok[8];
  if (tid < 8) stok[tid] = tokens[s*BB + g*8 + tid];
  __syncthreads();
  // gather: row rr = tid>>5 (8 rows x 32 lanes), d = (tid&31) + 32j.
  // Each thread's elements belong to ONE row -> clean per-row reduction.
  {
    const int rr = tid >> 5, l = tid & 31;
    const float* row = emb + (size_t)stok[rr]*DE;
    double sum = 0.0, sq = 0.0;
    #pragma unroll
    for (int j = 0; j < 19; ++j) {
      int d = l + 32*j;
      if (d < DD) {
        float v = (d < DE) ? row[d] * SQD
                           : pos[(s*BB + g*8 + rr)*3 + (d - DE)];
        xs[rr*DD + d] = v;
        sum += v; sq += (double)v*v;
      }
    }
    // width-32 tree: lanes 0-31 / 32-63 reduce their own row independently
    for (int off = 16; off > 0; off >>= 1) {
      sum += __shfl_down(sum, off, 32);
      sq  += __shfl_down(sq, off, 32);
    }
    if (l == 0) {
      rowsumd[s*BB + g*8 + rr] = sum;
      rowsqd [s*BB + g*8 + rr] = sq;
    }
  }
  __syncthreads();
  // conv: up=tid&127 -> u, oh=tid>>7 -> o in [8oh, 8oh+8)
  const int up = tid & 127;
  const int oh = __builtin_amdgcn_readfirstlane(tid >> 7);  // wave-uniform
  const int u  = (up < U1) ? up : (U1 - 1);
  float acc[8] = {0,0,0,0,0,0,0,0};
  for (int cc = 0; cc < 8; ++cc) {
    const float* xr = &xs[cc*DD + 5*u];   // stride-5 lanes: conflict-free
    float xv[21];
    #pragma unroll
    for (int m = 0; m < 21; ++m) xv[m] = xr[m];
    float xw[17];
    #pragma unroll
    for (int k = 0; k < 17; ++k)
      xw[k] = ((xv[k] + xv[k+1]) + (xv[k+2] + xv[k+3])) + xv[k+4];
    #pragma unroll
    for (int j = 0; j < 8; ++j) {
      // wave-uniform base -> scalar loads, no LDS traffic for weights
      const float* wj = w1 + ((size_t)(oh*8 + j)*BB + (g*8 + cc))*17;
      float a = 0.f;
      #pragma unroll
      for (int k = 0; k < 17; ++k) a += xw[k] * wj[k];
      acc[j] += a;
    }
  }
  if (up < U1) {
    float* pb = part + ((size_t)(g*SS + s)*16 + oh*8)*U1 + up;
    #pragma unroll
    for (int j = 0; j < 8; ++j) pb[j*U1] = acc[j] * 0.2f;  // coalesced
  }
}

// ---- K2: stats -> affine assembly, pool2, conv2, conv3, dense, argmax ----
__global__ __launch_bounds__(256) void k_tail(
    const double* __restrict__ rowsumd, const double* __restrict__ rowsqd,
    const float* __restrict__ gamma, const float* __restrict__ beta,
    const float* __restrict__ part, const float* __restrict__ w1,
    const float* __restrict__ b1, const float* __restrict__ w2,
    const float* __restrict__ b2, const float* __restrict__ w3,
    const float* __restrict__ b3, const float* __restrict__ wl,
    const float* __restrict__ bl, float* __restrict__ out)
{
  const int s = blockIdx.x, tid = threadIdx.x;
  __shared__ float o2[16*U1];
  __shared__ float p2[16*U2];
  __shared__ float o4[8*U2];
  __shared__ float o5[32*T3];
  __shared__ float wlb[128*37];   // +1 pad: conflict-free
  __shared__ float blb[128];
  __shared__ float wsumb[16];
  __shared__ float sAl, sDe;
  for (int idx = tid; idx < 128*36; idx += 256) {
    int v = idx / 36, t = idx - v*36;
    wlb[v*37 + t] = wl[idx];
  }
  if (tid < 128) blb[tid] = bl[tid];
  // wsum[o] = sum over c,k of w1[o][c][k] = sum of 544 contiguous floats
  {
    const int o = tid >> 4, i = tid & 15;
    float acc = 0.f;
    for (int j = i; j < BB*17; j += 16) acc += w1[o*BB*17 + j];
    for (int off = 8; off > 0; off >>= 1) acc += __shfl_down(acc, off, 16);
    if (i == 0) wsumb[o] = acc;
  }
  // deterministic stats reduce (32 doubles, fixed tree) -> al, de
  if (tid < 32) {
    double sm = rowsumd[s*BB + tid], qq = rowsqd[s*BB + tid];
    for (int off = 16; off > 0; off >>= 1) {
      sm += __shfl_down(sm, off, 32);
      qq += __shfl_down(qq, off, 32);
    }
    if (tid == 0) {
      double m0d = sm / (double)NTOK;
      float m0 = (float)m0d;
      float v0 = (float)(qq / (double)NTOK - m0d*m0d);
      float a = 1.0f;
      for (int l = 0; l < 4; ++l) {
        float r = 1.0f / sqrtf(a*a*v0 + 1e-5f);
        a = gamma[l*SS + s] * r * a;
      }
      sAl = a;
      sDe = beta[3*SS + s] - a*m0;
    }
  }
  __syncthreads();
  const float al = sAl, de = sDe;
  for (int idx = tid; idx < 16*U1; idx += 256) {
    int o = idx / U1;
    float psum = part[(size_t)(0*SS + s)*16*U1 + idx]
               + part[(size_t)(1*SS + s)*16*U1 + idx]
               + part[(size_t)(2*SS + s)*16*U1 + idx]
               + part[(size_t)(3*SS + s)*16*U1 + idx];
    o2[idx] = al*psum + de*wsumb[o] + b1[o];
  }
  __syncthreads();
  for (int i2 = tid; i2 < 16*U2; i2 += 256) {   // 608 > 256: loop required
    int o = i2 / U2, v = i2 - o*U2;
    p2[i2] = (o2[o*U1 + 3*v] + o2[o*U1 + 3*v+1] + o2[o*U1 + 3*v+2]) * (1.f/3.f);
  }
  __syncthreads();
  for (int i2 = tid; i2 < 8*U2; i2 += 256) {    // 304 > 256: loop required
    int p = i2 / U2, v = i2 - p*U2;
    float acc = b2[p];
    #pragma unroll
    for (int o = 0; o < 16; ++o) acc += p2[o*U2 + v] * w2[p*16 + o];
    o4[i2] = acc;
  }
  __syncthreads();
  for (int i2 = tid; i2 < 32*T3; i2 += 256) {   // 1152 > 256: loop required
    int q = i2 / T3, t = i2 - q*T3;
    float acc = b3[q];
    #pragma unroll
    for (int p = 0; p < 8; ++p) {
      acc += o4[p*U2 + t    ] * w3[(q*8+p)*3 + 0]
           + o4[p*U2 + t + 1] * w3[(q*8+p)*3 + 1]
           + o4[p*U2 + t + 2] * w3[(q*8+p)*3 + 2];
    }
    o5[i2] = acc;
  }
  __syncthreads();
  // 256 threads: q = tid>>3 covers 0..31, vs = tid&7; v = vs + 8*i ascending
  // per thread; (max,min-idx) merge preserves first-max tie-break.
  const int q = tid >> 3, vs = tid & 7;
  float best = -1e30f; int bidx = 0;
  const float* orow = &o5[q*T3];
  for (int i = 0; i < 16; ++i) {
    int v = vs + 8*i;
    float acc = blb[v];
    const float* wr = &wlb[v*37];
    #pragma unroll
    for (int t = 0; t < 36; ++t) acc += orow[t] * wr[t];
    if (acc > best) { best = acc; bidx = v; }
  }
  #pragma unroll
  for (int off = 1; off < 8; off <<= 1) {
    float ov = __shfl_xor(best, off);
    int oi = __shfl_xor(bidx, off);
    if (ov > best || (ov == best && oi < bidx)) { best = ov; bidx = oi; }
  }
  if (vs == 0) out[s*BB + q] = (float)bidx;
}

extern "C" void kernel_launch(void* const* d_in, const int* in_sizes, int n_in,
                              void* d_out, int out_size, void* d_ws, size_t ws_size,
                              hipStream_t stream)
{
  const int*   tokens = (const int*)  d_in[0];
  const float* emb    = (const float*)d_in[1];
  const float* pos    = (const float*)d_in[2];
  const float* gamma  = (const float*)d_in[3];
  const float* beta   = (const float*)d_in[4];
  const float* w1     = (const float*)d_in[5];
  const float* b1     = (const float*)d_in[6];
  const float* w2     = (const float*)d_in[7];
  const float* b2     = (const float*)d_in[8];
  const float* w3     = (const float*)d_in[9];
  const float* b3     = (const float*)d_in[10];
  const float* wl     = (const float*)d_in[11];
  const float* bl     = (const float*)d_in[12];
  float* out = (float*)d_out;

  double* rowsumd = (double*)d_ws;            // 2048
  double* rowsqd  = rowsumd + NSTAT;          // 2048
  float*  part    = (float*)(rowsqd + NSTAT); // 4*64*16*114

  k_main<<<dim3(SS, 4), dim3(256), 0, stream>>>(
      tokens, emb, pos, w1, rowsumd, rowsqd, part);
  k_tail<<<dim3(SS), dim3(256), 0, stream>>>(
      rowsumd, rowsqd, gamma, beta, part, w1, b1, w2, b2, w3, b3,
      wl, bl, out);
}